// Round 8
// baseline (13980.145 us; speedup 1.0000x reference)
//
#include <hip/hip_runtime.h>
#include <stdint.h>

// D = 4096, TOKENS = (4,2048) -> M = 8192.
#define DD 4096
#define NE_IDX 3277   // round(4096*0.8)

typedef __attribute__((ext_vector_type(8))) short short8;
typedef __attribute__((ext_vector_type(16))) float f32x16;
typedef __attribute__((ext_vector_type(4))) unsigned int u32x4;

__device__ __forceinline__ unsigned short f2bf(float f) {
    unsigned int u = __float_as_uint(f);
    u += 0x7fffu + ((u >> 16) & 1u);
    return (unsigned short)(u >> 16);
}

__device__ __forceinline__ void gload16(const void* g, void* l) {
    __builtin_amdgcn_global_load_lds(
        (const __attribute__((address_space(1))) unsigned int*)g,
        (__attribute__((address_space(3))) unsigned int*)l,
        16, 0, 0);
}

#define VMC4 asm volatile("s_waitcnt vmcnt(4)" ::: "memory")
#define VMC2 asm volatile("s_waitcnt vmcnt(2)" ::: "memory")
#define VMC0 asm volatile("s_waitcnt vmcnt(0)" ::: "memory")
#define LGKM8 do { asm volatile("s_waitcnt lgkmcnt(8)" ::: "memory"); \
                   __builtin_amdgcn_sched_barrier(0); } while (0)
#define LGKM0 do { asm volatile("s_waitcnt lgkmcnt(0)" ::: "memory"); \
                   __builtin_amdgcn_sched_barrier(0); } while (0)
#define BAR  __builtin_amdgcn_s_barrier()

// ---------------------------------------------------------------------------
__global__ void detect_kernel(const unsigned int* __restrict__ k0, int* __restrict__ flag) {
    if (blockIdx.x == 0 && threadIdx.x == 0) {
        int ok4 = 1;
        for (int i = 0; i < 256; ++i) {
            unsigned int v = k0[i];
            if (!(v == 0u || v == 1u || v == 0x3f800000u)) { ok4 = 0; break; }
        }
        *flag = ok4;
    }
}

// ---------------------------------------------------------------------------
__global__ void pack_x_kernel(const float* __restrict__ x, unsigned short* __restrict__ xb, int n8) {
    const int stride = gridDim.x * blockDim.x;
    for (int i = blockIdx.x * blockDim.x + threadIdx.x; i < n8; i += stride) {
        const float4* p = (const float4*)(x + (size_t)i * 8);
        float4 a = p[0], b = p[1];
        short8 r;
        r[0] = (short)f2bf(a.x); r[1] = (short)f2bf(a.y);
        r[2] = (short)f2bf(a.z); r[3] = (short)f2bf(a.w);
        r[4] = (short)f2bf(b.x); r[5] = (short)f2bf(b.y);
        r[6] = (short)f2bf(b.z); r[7] = (short)f2bf(b.w);
        *(short8*)(xb + (size_t)i * 8) = r;
    }
}

// ---------------------------------------------------------------------------
// wt[j*DD + i] = s * (i < ne ? 1 : inh) * (k[i][j] ? 1 : -1), 64x64 LDS transpose
// ---------------------------------------------------------------------------
__global__ void pack_w_kernel(const void* __restrict__ kin, unsigned short* __restrict__ wt,
                              const float* __restrict__ sptr, float inh, int ne,
                              const int* __restrict__ flag) {
    __shared__ unsigned short tile[64][68];
    const int elem4 = *flag;
    const float s = *sptr;
    const int i0 = blockIdx.x * 64;
    const int j0 = blockIdx.y * 64;
    const int t = threadIdx.x;
    {
        const int il = t >> 2;
        const int jc = (t & 3) * 16;
        const int gi = i0 + il;
        const float mag = s * ((gi < ne) ? 1.0f : inh);
        const unsigned short pos = f2bf(mag);
        const unsigned short neg = f2bf(-mag);
        if (elem4) {
            const unsigned int* k32 = (const unsigned int*)kin + (size_t)gi * DD + j0 + jc;
            #pragma unroll
            for (int q = 0; q < 4; ++q) {
                u32x4 v = *(const u32x4*)(k32 + q * 4);
                #pragma unroll
                for (int e = 0; e < 4; ++e)
                    tile[il][jc + q * 4 + e] = v[e] ? pos : neg;
            }
        } else {
            const unsigned char* k8 = (const unsigned char*)kin + (size_t)gi * DD + j0 + jc;
            u32x4 v = *(const u32x4*)k8;
            #pragma unroll
            for (int q = 0; q < 4; ++q) {
                unsigned int w = v[q];
                tile[il][jc + q * 4 + 0] = (w & 0xffu) ? pos : neg;
                tile[il][jc + q * 4 + 1] = ((w >> 8) & 0xffu) ? pos : neg;
                tile[il][jc + q * 4 + 2] = ((w >> 16) & 0xffu) ? pos : neg;
                tile[il][jc + q * 4 + 3] = ((w >> 24) & 0xffu) ? pos : neg;
            }
        }
    }
    __syncthreads();
    {
        const int jl = t >> 2;
        const int ic = (t & 3) * 16;
        short8 o0, o1;
        #pragma unroll
        for (int e = 0; e < 8; ++e) o0[e] = (short)tile[ic + e][jl];
        #pragma unroll
        for (int e = 0; e < 8; ++e) o1[e] = (short)tile[ic + 8 + e][jl];
        unsigned short* dst = wt + (size_t)(j0 + jl) * DD + i0 + ic;
        *(short8*)(dst) = o0;
        *(short8*)(dst + 8) = o1;
    }
}

// ---------------------------------------------------------------------------
// 256x256 tile, BK=64, 8 waves (2Mx4N), 32x32x16 MFMA, double-row LDS layout
// (conflict-free). 2 phases/tile, 16-MFMA clusters with 4 interleaved acc
// chains (s -> nh -> mi; dep distance 4 ~= 32 cyc) for MFMA-pipe ILP.
// Read-ahead: Ph0 reads af1(t), Ph1 reads af0(t+1) then bf(t+1) after MFMA;
// every lgkmcnt(8) targets reads issued a full phase earlier.
// Staging: Ph0 {A0',B0',B1'} (6 gloads) + vmcnt(4); Ph1 {A1'} (2) + vmcnt(2).
// FIFO proof (steady state, 2 loads/site):
//  t.Ph0 after stages: [A1(t), A0',B0',B1'] (8) --vmcnt(4)--> A1(t) landed
//        => RD af1(t) ok; lgkmcnt(8) retires af0(t),bf(t) (16 older reads).
//  t.Ph1 after stage:  [A0',B0',B1', A1'] (8) --vmcnt(2)--> A0',B0',B1'
//        landed => RD af0(t+1) + bf(t+1) ok; lgkmcnt(8) retires af1(t).
// Prologue vmcnt(2) (leaves A1(0)) + RD af0(0),bf(0) = same invariant.
// Cross-wave visibility: every read of staged data follows the barrier that
// follows the counted vmcnt retiring it. WAR: stages write the idle buffer.
// ---------------------------------------------------------------------------
template <int MODE>
__global__ __launch_bounds__(512, 2)
void gemm256_kernel(const unsigned short* __restrict__ A,   // M x 4096 bf16
                    const unsigned short* __restrict__ Bt,  // 4096 x 4096 bf16 (N x K)
                    void* __restrict__ Cout)
{
    __shared__ unsigned short L[65536];  // 128 KiB: buf0{A,B} buf1{A,B}
    const char* Lc = (const char*)L;

    const int tid  = threadIdx.x;
    const int lane = tid & 63;
    const int l31  = lane & 31;
    const int hb   = lane >> 5;          // k-half select
    const int wave = tid >> 6;
    const int wr   = wave >> 2;    // 0..1
    const int wc   = wave & 3;     // 0..3

    // XCD swizzle (grid = 512, divisible by 8)
    int wg = blockIdx.x;
    const int per = gridDim.x >> 3;
    wg = (wg & 7) * per + (wg >> 3);
    const int tm = wg >> 4;        // 32 M-tiles
    const int tn = wg & 15;        // 16 N-tiles

    const size_t arow0 = (size_t)tm * 256;
    const size_t brow0 = (size_t)tn * 256;

    // --- staging constants (slot involution pre-applied to global source) ---
    const int sx  = (tid & 15) ^ ((tid >> 4) & 15);
    const int kcS = (sx & 7) << 3;                 // k element offset 0..56
    const int rbS = sx >> 3;                       // row parity
    const int arowloc = ((tid >> 4) << 1) + rbS;   // 0..63 within A site
    const int lcl = tid & 255;
    const int seg = tid >> 8;
    const int browloc = ((lcl >> 4) << 1) + rbS;   // 0..31 within B segment

    // A site (c,q): drows [c*32+q*64, +32), global rows c*64+q*128+[0,64)
    auto stageA = [&](int sb, int c, int kt) {
        #pragma unroll
        for (int q = 0; q < 2; ++q) {
            gload16(A + ((arow0 + c * 64 + q * 128 + arowloc) << 12) + kt + kcS,
                    (void*)&L[sb + (c * 32 + q * 64) * 128 + tid * 8]);
        }
    };
    // B site (c,q): drows {c*16+seg*32+q*64}, global cols = drow*2+browloc
    auto stageB = [&](int sb, int c, int kt) {
        #pragma unroll
        for (int q = 0; q < 2; ++q) {
            const int d0 = c * 16 + seg * 32 + q * 64;
            gload16(Bt + ((brow0 + d0 * 2 + browloc) << 12) + kt + kcS,
                    (void*)&L[sb + 16384 + d0 * 128 + lcl * 8]);
        }
    };

    // --- ds_read byte bases (double-row + slot swizzle; step s: XOR s<<5) ---
    const int slot0 = (hb | ((l31 & 1) << 3)) ^ (l31 >> 1);
    int abase = ((wr * 64 + (l31 >> 1)) << 8) + (slot0 << 4);
    int bbase = 32768 + ((wc * 32 + (l31 >> 1)) << 8) + (slot0 << 4);

    short8 af[2][2][4];   // [half][mi][s]
    short8 bf[2][4];      // [half][s]
    f32x16 acc[4][2];
    #pragma unroll
    for (int m = 0; m < 4; ++m)
        #pragma unroll
        for (int n = 0; n < 2; ++n)
            #pragma unroll
            for (int e = 0; e < 16; ++e)
                acc[m][n][e] = 0.f;

    auto RD_A = [&](int h) {
        #pragma unroll
        for (int s = 0; s < 4; ++s)
            #pragma unroll
            for (int mi = 0; mi < 2; ++mi)
                af[h][mi][s] = *(const short8*)(Lc + (abase ^ (s << 5)) + ((h * 2 + mi) << 12));
    };
    auto RD_B = [&]() {
        #pragma unroll
        for (int s = 0; s < 4; ++s)
            #pragma unroll
            for (int h = 0; h < 2; ++h)
                bf[h][s] = *(const short8*)(Lc + (bbase ^ (s << 5)) + (h << 12));
    };
    // 16 MFMA, 4 chains (mi,nh), dep distance 4 (~32 cyc) per chain
    auto MM16 = [&](int mh) {
        __builtin_amdgcn_s_setprio(1);
        #pragma unroll
        for (int s = 0; s < 4; ++s)
            #pragma unroll
            for (int nh = 0; nh < 2; ++nh)
                #pragma unroll
                for (int mi = 0; mi < 2; ++mi)
                    acc[mh * 2 + mi][nh] = __builtin_amdgcn_mfma_f32_32x32x16_bf16(
                        af[mh][mi][s], bf[nh][s], acc[mh * 2 + mi][nh], 0, 0, 0);
        __builtin_amdgcn_s_setprio(0);
        __builtin_amdgcn_sched_barrier(0);
    };

    // prologue: tile0 A0,B0,B1,A1 -> buf0; vmcnt(2) => A0,B0,B1 landed;
    // pre-read af0(0)+bf(0)  (steady-state entry invariant)
    stageA(0, 0, 0); stageB(0, 0, 0); stageB(0, 1, 0); stageA(0, 1, 0);
    VMC2; BAR;
    __builtin_amdgcn_sched_barrier(0);
    RD_A(0); RD_B();

    for (int t = 0; t < 63; ++t) {
        const int sb  = ((t + 1) & 1) * 32768;  // idle buffer (tile t+1)
        const int kt2 = (t + 1) * 64;
        // Ph0: MFMA half 0; read af1(t)
        stageA(sb, 0, kt2); stageB(sb, 0, kt2); stageB(sb, 1, kt2);
        VMC4; BAR;
        RD_A(1); LGKM8;
        MM16(0);
        // Ph1: MFMA half 1; read af0(t+1), then bf(t+1)
        stageA(sb, 1, kt2);
        VMC2; BAR;
        abase ^= 65536; bbase ^= 65536;
        RD_A(0); LGKM8;
        MM16(1);
        RD_B();
    }
    // tail: tile 63 (bases already point at buf1), no staging
    VMC0; BAR;
    RD_A(1); LGKM8;
    MM16(0);
    LGKM0;
    MM16(1);

    // epilogue: C/D col = lane&31, row = (reg&3) + 8*(reg>>2) + 4*(lane>>5)
    const int orow0 = tm * 256 + wr * 128 + hb * 4;
    const int ocol0 = tn * 256 + wc * 64 + l31;
    #pragma unroll
    for (int mt = 0; mt < 4; ++mt) {
        #pragma unroll
        for (int nt = 0; nt < 2; ++nt) {
            #pragma unroll
            for (int reg = 0; reg < 16; ++reg) {
                const int row = orow0 + mt * 32 + (reg & 3) + 8 * (reg >> 2);
                const int col = ocol0 + nt * 32;
                float v = acc[mt][nt][reg];
                if (MODE == 1) {
                    v = fmaxf(v, 0.0f) * 2.0f;
                    ((unsigned short*)Cout)[((size_t)row << 12) + col] = f2bf(v);
                } else {
                    ((float*)Cout)[((size_t)row << 12) + col] = v;
                }
            }
        }
    }
}

// ---------------------------------------------------------------------------
extern "C" void kernel_launch(void* const* d_in, const int* in_sizes, int n_in,
                              void* d_out, int out_size, void* d_ws, size_t ws_size,
                              hipStream_t stream) {
    const float* x  = (const float*)d_in[0];
    const void*  k0 = d_in[1];
    const float* s0 = (const float*)d_in[2];
    const void*  k1 = d_in[3];
    const float* s1 = (const float*)d_in[4];
    const void*  k2 = d_in[5];
    const float* s2 = (const float*)d_in[6];

    const int M = in_sizes[0] / DD;   // 8192

    const size_t act_bytes = (size_t)M * DD * 2;
    const size_t w_bytes   = (size_t)DD * DD * 2;
    const size_t need      = act_bytes * 2 + w_bytes + 256;
    if (ws_size < need) return;

    char* ws = (char*)d_ws;
    unsigned short* xb = (unsigned short*)ws;                        // M x DD bf16 (later h2)
    unsigned short* h1 = (unsigned short*)(ws + act_bytes);          // M x DD bf16
    unsigned short* wt = (unsigned short*)(ws + act_bytes * 2);      // DD x DD bf16 (N x K)
    int* flag          = (int*)(ws + act_bytes * 2 + w_bytes);

    detect_kernel<<<1, 64, 0, stream>>>((const unsigned int*)k0, flag);
    pack_x_kernel<<<2048, 256, 0, stream>>>(x, xb, M * DD / 8);

    dim3 pw_grid(DD / 64, DD / 64);
    const int gemm_grid = (M / 256) * (DD / 256);   // 512

    // layer 0: h1 = relu(s0 * x @ W0) * 2
    pack_w_kernel<<<pw_grid, 256, 0, stream>>>(k0, wt, s0, 1.0f, DD, flag);
    gemm256_kernel<1><<<gemm_grid, 512, 0, stream>>>(xb, wt, h1);

    // layer 1: h2 = relu(ei_dense(h1, k1, s1)) * 2
    pack_w_kernel<<<pw_grid, 256, 0, stream>>>(k1, wt, s1, -4.0f, NE_IDX, flag);
    gemm256_kernel<1><<<gemm_grid, 512, 0, stream>>>(h1, wt, xb);

    // layer 2: out = ei_dense(h2, k2, s2), fp32
    pack_w_kernel<<<pw_grid, 256, 0, stream>>>(k2, wt, s2, -4.0f, NE_IDX, flag);
    gemm256_kernel<0><<<gemm_grid, 512, 0, stream>>>(xb, wt, (float*)d_out);
}

// Round 9
// 743.338 us; speedup vs baseline: 18.8073x; 18.8073x over previous
//
#include <hip/hip_runtime.h>
#include <stdint.h>

// D = 4096, TOKENS = (4,2048) -> M = 8192.
#define DD 4096
#define NE_IDX 3277   // round(4096*0.8)

typedef __attribute__((ext_vector_type(8))) short short8;
typedef __attribute__((ext_vector_type(4))) float f32x4;
typedef __attribute__((ext_vector_type(4))) unsigned int u32x4;

__device__ __forceinline__ unsigned short f2bf(float f) {
    unsigned int u = __float_as_uint(f);
    u += 0x7fffu + ((u >> 16) & 1u);
    return (unsigned short)(u >> 16);
}

__device__ __forceinline__ void gload16(const void* g, void* l) {
    __builtin_amdgcn_global_load_lds(
        (const __attribute__((address_space(1))) unsigned int*)g,
        (__attribute__((address_space(3))) unsigned int*)l,
        16, 0, 0);
}

#define BAR  __builtin_amdgcn_s_barrier()

// ---------------------------------------------------------------------------
__global__ void detect_kernel(const unsigned int* __restrict__ k0, int* __restrict__ flag) {
    if (blockIdx.x == 0 && threadIdx.x == 0) {
        int ok4 = 1;
        for (int i = 0; i < 256; ++i) {
            unsigned int v = k0[i];
            if (!(v == 0u || v == 1u || v == 0x3f800000u)) { ok4 = 0; break; }
        }
        *flag = ok4;
    }
}

// ---------------------------------------------------------------------------
__global__ void pack_x_kernel(const float* __restrict__ x, unsigned short* __restrict__ xb, int n8) {
    const int stride = gridDim.x * blockDim.x;
    for (int i = blockIdx.x * blockDim.x + threadIdx.x; i < n8; i += stride) {
        const float4* p = (const float4*)(x + (size_t)i * 8);
        float4 a = p[0], b = p[1];
        short8 r;
        r[0] = (short)f2bf(a.x); r[1] = (short)f2bf(a.y);
        r[2] = (short)f2bf(a.z); r[3] = (short)f2bf(a.w);
        r[4] = (short)f2bf(b.x); r[5] = (short)f2bf(b.y);
        r[6] = (short)f2bf(b.z); r[7] = (short)f2bf(b.w);
        *(short8*)(xb + (size_t)i * 8) = r;
    }
}

// ---------------------------------------------------------------------------
// wt[j*DD + i] = s * (i < ne ? 1 : inh) * (k[i][j] ? 1 : -1), 64x64 LDS transpose
// ---------------------------------------------------------------------------
__global__ void pack_w_kernel(const void* __restrict__ kin, unsigned short* __restrict__ wt,
                              const float* __restrict__ sptr, float inh, int ne,
                              const int* __restrict__ flag) {
    __shared__ unsigned short tile[64][68];
    const int elem4 = *flag;
    const float s = *sptr;
    const int i0 = blockIdx.x * 64;
    const int j0 = blockIdx.y * 64;
    const int t = threadIdx.x;
    {
        const int il = t >> 2;
        const int jc = (t & 3) * 16;
        const int gi = i0 + il;
        const float mag = s * ((gi < ne) ? 1.0f : inh);
        const unsigned short pos = f2bf(mag);
        const unsigned short neg = f2bf(-mag);
        if (elem4) {
            const unsigned int* k32 = (const unsigned int*)kin + (size_t)gi * DD + j0 + jc;
            #pragma unroll
            for (int q = 0; q < 4; ++q) {
                u32x4 v = *(const u32x4*)(k32 + q * 4);
                #pragma unroll
                for (int e = 0; e < 4; ++e)
                    tile[il][jc + q * 4 + e] = v[e] ? pos : neg;
            }
        } else {
            const unsigned char* k8 = (const unsigned char*)kin + (size_t)gi * DD + j0 + jc;
            u32x4 v = *(const u32x4*)k8;
            #pragma unroll
            for (int q = 0; q < 4; ++q) {
                unsigned int w = v[q];
                tile[il][jc + q * 4 + 0] = (w & 0xffu) ? pos : neg;
                tile[il][jc + q * 4 + 1] = ((w >> 8) & 0xffu) ? pos : neg;
                tile[il][jc + q * 4 + 2] = ((w >> 16) & 0xffu) ? pos : neg;
                tile[il][jc + q * 4 + 3] = ((w >> 24) & 0xffu) ? pos : neg;
            }
        }
    }
    __syncthreads();
    {
        const int jl = t >> 2;
        const int ic = (t & 3) * 16;
        short8 o0, o1;
        #pragma unroll
        for (int e = 0; e < 8; ++e) o0[e] = (short)tile[ic + e][jl];
        #pragma unroll
        for (int e = 0; e < 8; ++e) o1[e] = (short)tile[ic + 8 + e][jl];
        unsigned short* dst = wt + (size_t)(j0 + jl) * DD + i0 + ic;
        *(short8*)(dst) = o0;
        *(short8*)(dst + 8) = o1;
    }
}

// ---------------------------------------------------------------------------
// m201-faithful port: 256x256 tile, BK=64, 8 waves (2Mx4N), 16x16x32 MFMA,
// 8 phases / 2 K-tiles per iteration (tile u -> buf0, u+1 -> buf1).
// Per phase: {frag ds_reads ; 1 stage site (2 gload_lds) ; BARRIER ;
// lgkmcnt(0) ; setprio(1) ; 16 MFMA ; setprio(0) ; [vmcnt(4) @P4/P8 only] ;
// BARRIER}.  Counted vmcnt twice per iteration, never 0 in main loop.
// Stage sites: P1:Ah1(u+1) P2:Bh0(u+1) P3:Ah0(u+2) P4:Bh1(u+2)
//              P5:Bh0(u+2) P6:Ah1(u+2) P7:Ah0(u+3) P8:Bh1(u+3)
// FIFO proof (2 loads/site): entering P1, outstanding = {Ah0(u+1),Bh1(u+1)}
//  (prev P7,P8). At P4-end: 12 outstanding, vmcnt(4) retires through P2 =>
//  tile u+1 complete for P5..P8. At P8-end: 12 outstanding, vmcnt(4) retires
//  through P6 => tile u+2 complete for next P1..P4. WAR: each stage's dest
//  region's last reader is >=1 phase-end barrier earlier (A-chunk0 last read
//  P2/P6; A-chunk1 P3/P7; B-chunk0 P4/P8; B-chunk1 P3/P7).
// Prologue: tile0 (4 sites) + Ah0(1),Bh1(1); vmcnt(4) == steady invariant.
// Tail iter: stages only Ah1(63),Bh0(63); vmcnt(0) at P4.
// ---------------------------------------------------------------------------
#define PHASE(MH, NH, LA, LB, STAGE_STMT, VM) do {                              \
    if (LA) {                                                                   \
        _Pragma("unroll")                                                       \
        for (int m = 0; m < 4; ++m) {                                           \
            af[0][m] = *(const short8*)(Lc + (ab[(MH)*4+m] ^ kx0));             \
            af[1][m] = *(const short8*)(Lc + (ab[(MH)*4+m] ^ kx1));             \
        }                                                                       \
    }                                                                           \
    if (LB) {                                                                   \
        _Pragma("unroll")                                                       \
        for (int n = 0; n < 2; ++n) {                                           \
            bfr[0][n] = *(const short8*)(Lc + (bb[(NH)*2+n] ^ kx0));            \
            bfr[1][n] = *(const short8*)(Lc + (bb[(NH)*2+n] ^ kx1));            \
        }                                                                       \
    }                                                                           \
    STAGE_STMT;                                                                 \
    __builtin_amdgcn_s_barrier();                                               \
    asm volatile("s_waitcnt lgkmcnt(0)" ::: "memory");                          \
    __builtin_amdgcn_sched_barrier(0);                                          \
    __builtin_amdgcn_s_setprio(1);                                              \
    _Pragma("unroll")                                                           \
    for (int kk = 0; kk < 2; ++kk)                                              \
        _Pragma("unroll")                                                       \
        for (int m = 0; m < 4; ++m)                                             \
            _Pragma("unroll")                                                   \
            for (int n = 0; n < 2; ++n)                                         \
                acc[(MH)*4+m][(NH)*2+n] = __builtin_amdgcn_mfma_f32_16x16x32_bf16( \
                    af[kk][m], bfr[kk][n], acc[(MH)*4+m][(NH)*2+n], 0, 0, 0);   \
    __builtin_amdgcn_s_setprio(0);                                              \
    __builtin_amdgcn_sched_barrier(0);                                          \
    if ((VM) == 1) asm volatile("s_waitcnt vmcnt(4)" ::: "memory");             \
    if ((VM) == 2) asm volatile("s_waitcnt vmcnt(0)" ::: "memory");             \
    __builtin_amdgcn_s_barrier();                                               \
} while (0)

template <int MODE>
__global__ __launch_bounds__(512, 2)
void gemm256_kernel(const unsigned short* __restrict__ A,   // M x 4096 bf16
                    const unsigned short* __restrict__ Bt,  // 4096 x 4096 bf16 (N x K)
                    void* __restrict__ Cout)
{
    __shared__ unsigned short L[65536];  // 128 KiB: buf0{A,B} buf1{A,B}
    const char* Lc = (const char*)L;

    const int tid  = threadIdx.x;
    const int lane = tid & 63;
    const int fr   = lane & 15;
    const int fg   = lane >> 4;
    const int wave = tid >> 6;
    const int wr   = wave >> 2;    // 0..1
    const int wc   = wave & 3;     // 0..3

    // XCD swizzle (grid = 512, divisible by 8)
    int wg = blockIdx.x;
    const int per = gridDim.x >> 3;
    wg = (wg & 7) * per + (wg >> 3);
    const int tm = wg >> 4;        // 32 M-tiles
    const int tn = wg & 15;        // 16 N-tiles

    const size_t arow0 = (size_t)tm * 256;
    const size_t brow0 = (size_t)tn * 256;

    // staging: thread tid handles round-row rq = tid>>3, 16B chunk tid&7
    const int rq = tid >> 3;
    const int wq = (tid >> 6) << 3;
    const int srcoff = (((tid & 7) ^ ((tid >> 3) & 7)) << 3);

    // A chunk c = rows [c*64,+64) u [c*64+128,+64)  (== mh=c frag rows)
    auto stageA = [&](int sb, int c, int kt) {
        #pragma unroll
        for (int q = 0; q < 2; ++q) {
            const int dr = c * 64 + q * 128 + rq;
            gload16(A + ((arow0 + dr) << 12) + kt + srcoff,
                    (void*)&L[sb + ((c * 64 + q * 128 + wq) << 6)]);
        }
    };
    // B chunk c = rows c*32 + [0,32) + 64k  (== nh=c frag rows, all wc)
    auto stageB = [&](int sb, int c, int kt) {
        #pragma unroll
        for (int q = 0; q < 2; ++q) {
            const int lr  = q * 64 + rq;
            const int dr  = c * 32 + (lr & 31) + (lr >> 5) * 64;
            const int wlr = q * 64 + wq;
            const int wdr = c * 32 + (wlr & 31) + (wlr >> 5) * 64;
            gload16(Bt + ((brow0 + dr) << 12) + kt + srcoff,
                    (void*)&L[sb + 16384 + (wdr << 6)]);
        }
    };

    // precomputed ds_read byte addresses (swizzle folded; XOR k-chunk/buffer)
    const int kx0 = fg << 4;
    const int kx1 = (4 + fg) << 4;
    int ab[8], bb[4];
    #pragma unroll
    for (int m = 0; m < 8; ++m) {
        const int r = wr * 128 + m * 16 + fr;
        ab[m] = r * 128 + ((r & 7) << 4);
    }
    #pragma unroll
    for (int n = 0; n < 4; ++n) {
        const int r = wc * 64 + n * 16 + fr;
        bb[n] = 32768 + r * 128 + ((r & 7) << 4);
    }

    short8 af[2][4], bfr[2][2];
    f32x4 acc[8][4];
    #pragma unroll
    for (int m = 0; m < 8; ++m)
        #pragma unroll
        for (int n = 0; n < 4; ++n)
            acc[m][n] = (f32x4){0.f, 0.f, 0.f, 0.f};

    // prologue: tile0 -> buf0 (4 sites) + Ah0(1),Bh1(1) -> buf1; vmcnt(4)
    // leaves {Ah0(1),Bh1(1)} in flight == steady-state entry invariant.
    stageA(0, 0, 0); stageA(0, 1, 0); stageB(0, 0, 0); stageB(0, 1, 0);
    stageA(32768, 0, 64); stageB(32768, 1, 64);
    asm volatile("s_waitcnt vmcnt(4)" ::: "memory");
    BAR;
    __builtin_amdgcn_sched_barrier(0);

    for (int t = 0; t < 31; ++t) {
        const int kt1 = (2 * t + 1) * 64;
        const int kt2 = (2 * t + 2) * 64;
        const int kt3 = (2 * t + 3) * 64;
        // tile u = 2t from buf0
        PHASE(0, 0, 1, 1, stageA(32768, 1, kt1), 0);   // P1: Ah1(u+1)
        PHASE(0, 1, 0, 1, stageB(32768, 0, kt1), 0);   // P2: Bh0(u+1)
        PHASE(1, 1, 1, 0, stageA(0, 0, kt2), 0);       // P3: Ah0(u+2)
        PHASE(1, 0, 0, 1, stageB(0, 1, kt2), 1);       // P4: Bh1(u+2), vmcnt(4)
        #pragma unroll
        for (int i = 0; i < 8; ++i) ab[i] ^= 65536;
        #pragma unroll
        for (int i = 0; i < 4; ++i) bb[i] ^= 65536;
        // tile u+1 from buf1
        PHASE(0, 0, 1, 1, stageB(0, 0, kt2), 0);       // P5: Bh0(u+2)
        PHASE(0, 1, 0, 1, stageA(0, 1, kt2), 0);       // P6: Ah1(u+2)
        PHASE(1, 1, 1, 0, stageA(32768, 0, kt3), 0);   // P7: Ah0(u+3)
        PHASE(1, 0, 0, 1, stageB(32768, 1, kt3), 1);   // P8: Bh1(u+3), vmcnt(4)
        #pragma unroll
        for (int i = 0; i < 8; ++i) ab[i] ^= 65536;
        #pragma unroll
        for (int i = 0; i < 4; ++i) bb[i] ^= 65536;
    }
    // tail iteration: tiles 62,63; stage only Ah1(63),Bh0(63); drain at P4
    {
        const int kt1 = 63 * 64;
        PHASE(0, 0, 1, 1, stageA(32768, 1, kt1), 0);
        PHASE(0, 1, 0, 1, stageB(32768, 0, kt1), 0);
        PHASE(1, 1, 1, 0, (void)0, 0);
        PHASE(1, 0, 0, 1, (void)0, 2);                 // vmcnt(0)
        #pragma unroll
        for (int i = 0; i < 8; ++i) ab[i] ^= 65536;
        #pragma unroll
        for (int i = 0; i < 4; ++i) bb[i] ^= 65536;
        PHASE(0, 0, 1, 1, (void)0, 0);
        PHASE(0, 1, 0, 1, (void)0, 0);
        PHASE(1, 1, 1, 0, (void)0, 0);
        PHASE(1, 0, 0, 1, (void)0, 0);
    }

    // epilogue: C/D layout col = lane&15, row = (lane>>4)*4 + reg
    const int orow0 = tm * 256 + wr * 128;
    const int ocol0 = tn * 256 + wc * 64;
    #pragma unroll
    for (int m = 0; m < 8; ++m) {
        #pragma unroll
        for (int n = 0; n < 4; ++n) {
            #pragma unroll
            for (int j = 0; j < 4; ++j) {
                const int row = orow0 + m * 16 + fg * 4 + j;
                const int col = ocol0 + n * 16 + fr;
                float v = acc[m][n][j];
                if (MODE == 1) {
                    v = fmaxf(v, 0.0f) * 2.0f;
                    ((unsigned short*)Cout)[((size_t)row << 12) + col] = f2bf(v);
                } else {
                    ((float*)Cout)[((size_t)row << 12) + col] = v;
                }
            }
        }
    }
}

// ---------------------------------------------------------------------------
extern "C" void kernel_launch(void* const* d_in, const int* in_sizes, int n_in,
                              void* d_out, int out_size, void* d_ws, size_t ws_size,
                              hipStream_t stream) {
    const float* x  = (const float*)d_in[0];
    const void*  k0 = d_in[1];
    const float* s0 = (const float*)d_in[2];
    const void*  k1 = d_in[3];
    const float* s1 = (const float*)d_in[4];
    const void*  k2 = d_in[5];
    const float* s2 = (const float*)d_in[6];

    const int M = in_sizes[0] / DD;   // 8192

    const size_t act_bytes = (size_t)M * DD * 2;
    const size_t w_bytes   = (size_t)DD * DD * 2;
    const size_t need      = act_bytes * 2 + w_bytes + 256;
    if (ws_size < need) return;

    char* ws = (char*)d_ws;
    unsigned short* xb = (unsigned short*)ws;                        // M x DD bf16 (later h2)
    unsigned short* h1 = (unsigned short*)(ws + act_bytes);          // M x DD bf16
    unsigned short* wt = (unsigned short*)(ws + act_bytes * 2);      // DD x DD bf16 (N x K)
    int* flag          = (int*)(ws + act_bytes * 2 + w_bytes);

    detect_kernel<<<1, 64, 0, stream>>>((const unsigned int*)k0, flag);
    pack_x_kernel<<<2048, 256, 0, stream>>>(x, xb, M * DD / 8);

    dim3 pw_grid(DD / 64, DD / 64);
    const int gemm_grid = (M / 256) * (DD / 256);   // 512

    // layer 0: h1 = relu(s0 * x @ W0) * 2
    pack_w_kernel<<<pw_grid, 256, 0, stream>>>(k0, wt, s0, 1.0f, DD, flag);
    gemm256_kernel<1><<<gemm_grid, 512, 0, stream>>>(xb, wt, h1);

    // layer 1: h2 = relu(ei_dense(h1, k1, s1)) * 2
    pack_w_kernel<<<pw_grid, 256, 0, stream>>>(k1, wt, s1, -4.0f, NE_IDX, flag);
    gemm256_kernel<1><<<gemm_grid, 512, 0, stream>>>(h1, wt, xb);

    // layer 2: out = ei_dense(h2, k2, s2), fp32
    pack_w_kernel<<<pw_grid, 256, 0, stream>>>(k2, wt, s2, -4.0f, NE_IDX, flag);
    gemm256_kernel<0><<<gemm_grid, 512, 0, stream>>>(xb, wt, (float*)d_out);
}

// Round 10
// 728.194 us; speedup vs baseline: 19.1984x; 1.0208x over previous
//
#include <hip/hip_runtime.h>
#include <stdint.h>

// D = 4096, TOKENS = (4,2048) -> M = 8192.
#define DD 4096
#define NE_IDX 3277   // round(4096*0.8)

typedef __attribute__((ext_vector_type(8))) short short8;
typedef __attribute__((ext_vector_type(4))) float f32x4;
typedef __attribute__((ext_vector_type(4))) unsigned int u32x4;

__device__ __forceinline__ unsigned short f2bf(float f) {
    unsigned int u = __float_as_uint(f);
    u += 0x7fffu + ((u >> 16) & 1u);
    return (unsigned short)(u >> 16);
}

__device__ __forceinline__ void gload16(const void* g, void* l) {
    __builtin_amdgcn_global_load_lds(
        (const __attribute__((address_space(1))) unsigned int*)g,
        (__attribute__((address_space(3))) unsigned int*)l,
        16, 0, 0);
}

// ---------------------------------------------------------------------------
__global__ void detect_kernel(const unsigned int* __restrict__ k0, int* __restrict__ flag) {
    if (blockIdx.x == 0 && threadIdx.x == 0) {
        int ok4 = 1;
        for (int i = 0; i < 256; ++i) {
            unsigned int v = k0[i];
            if (!(v == 0u || v == 1u || v == 0x3f800000u)) { ok4 = 0; break; }
        }
        *flag = ok4;
    }
}

// ---------------------------------------------------------------------------
__global__ void pack_x_kernel(const float* __restrict__ x, unsigned short* __restrict__ xb, int n8) {
    const int stride = gridDim.x * blockDim.x;
    for (int i = blockIdx.x * blockDim.x + threadIdx.x; i < n8; i += stride) {
        const float4* p = (const float4*)(x + (size_t)i * 8);
        float4 a = p[0], b = p[1];
        short8 r;
        r[0] = (short)f2bf(a.x); r[1] = (short)f2bf(a.y);
        r[2] = (short)f2bf(a.z); r[3] = (short)f2bf(a.w);
        r[4] = (short)f2bf(b.x); r[5] = (short)f2bf(b.y);
        r[6] = (short)f2bf(b.z); r[7] = (short)f2bf(b.w);
        *(short8*)(xb + (size_t)i * 8) = r;
    }
}

// ---------------------------------------------------------------------------
// wt[j*DD + i] = s * (i < ne ? 1 : inh) * (k[i][j] ? 1 : -1), 64x64 LDS transpose
// ---------------------------------------------------------------------------
__global__ void pack_w_kernel(const void* __restrict__ kin, unsigned short* __restrict__ wt,
                              const float* __restrict__ sptr, float inh, int ne,
                              const int* __restrict__ flag) {
    __shared__ unsigned short tile[64][68];
    const int elem4 = *flag;
    const float s = *sptr;
    const int i0 = blockIdx.x * 64;
    const int j0 = blockIdx.y * 64;
    const int t = threadIdx.x;
    {
        const int il = t >> 2;
        const int jc = (t & 3) * 16;
        const int gi = i0 + il;
        const float mag = s * ((gi < ne) ? 1.0f : inh);
        const unsigned short pos = f2bf(mag);
        const unsigned short neg = f2bf(-mag);
        if (elem4) {
            const unsigned int* k32 = (const unsigned int*)kin + (size_t)gi * DD + j0 + jc;
            #pragma unroll
            for (int q = 0; q < 4; ++q) {
                u32x4 v = *(const u32x4*)(k32 + q * 4);
                #pragma unroll
                for (int e = 0; e < 4; ++e)
                    tile[il][jc + q * 4 + e] = v[e] ? pos : neg;
            }
        } else {
            const unsigned char* k8 = (const unsigned char*)kin + (size_t)gi * DD + j0 + jc;
            u32x4 v = *(const u32x4*)k8;
            #pragma unroll
            for (int q = 0; q < 4; ++q) {
                unsigned int w = v[q];
                tile[il][jc + q * 4 + 0] = (w & 0xffu) ? pos : neg;
                tile[il][jc + q * 4 + 1] = ((w >> 8) & 0xffu) ? pos : neg;
                tile[il][jc + q * 4 + 2] = ((w >> 16) & 0xffu) ? pos : neg;
                tile[il][jc + q * 4 + 3] = ((w >> 24) & 0xffu) ? pos : neg;
            }
        }
    }
    __syncthreads();
    {
        const int jl = t >> 2;
        const int ic = (t & 3) * 16;
        short8 o0, o1;
        #pragma unroll
        for (int e = 0; e < 8; ++e) o0[e] = (short)tile[ic + e][jl];
        #pragma unroll
        for (int e = 0; e < 8; ++e) o1[e] = (short)tile[ic + 8 + e][jl];
        unsigned short* dst = wt + (size_t)(j0 + jl) * DD + i0 + ic;
        *(short8*)(dst) = o0;
        *(short8*)(dst + 8) = o1;
    }
}

// ---------------------------------------------------------------------------
// R3 champion structure: 256x256 tile, BK=64, 8 waves (2Mx4N), 4 phases/K-tile,
// 16x16x32 MFMA. Phase order (0,0),(0,1),(1,1),(1,0): reads 12/4/8/4.
// Per phase: [frag reads] -> stage 1 chunk -> vmcnt(4) -> barrier ->
// lgkmcnt(0) -> 16 MFMA (setprio) -> fence. End-barrier only at p3.
// Stage order A0',B0',B1',A1' at p0..p3 (deadline proof: round 3).
// NEW: MODE=1 epilogue goes through LDS (520B-stride staging, conflict-free)
// and stores full 512B contiguous rows -> fixes the 2x HBM write
// amplification of the strided 32B bf16 stores.
// ---------------------------------------------------------------------------
#define PHASE(MH, NH, LA, LB, STAGE_STMT, EB) do {                              \
    if (LA) {                                                                   \
        _Pragma("unroll")                                                       \
        for (int m = 0; m < 4; ++m) {                                           \
            af[0][m] = *(const short8*)(Lc + (ab[(MH)*4+m] ^ kx0));             \
            af[1][m] = *(const short8*)(Lc + (ab[(MH)*4+m] ^ kx1));             \
        }                                                                       \
    }                                                                           \
    if (LB) {                                                                   \
        _Pragma("unroll")                                                       \
        for (int n = 0; n < 2; ++n) {                                           \
            bfr[0][n] = *(const short8*)(Lc + (bb[(NH)*2+n] ^ kx0));            \
            bfr[1][n] = *(const short8*)(Lc + (bb[(NH)*2+n] ^ kx1));            \
        }                                                                       \
    }                                                                           \
    STAGE_STMT;                                                                 \
    asm volatile("s_waitcnt vmcnt(4)" ::: "memory");                            \
    __builtin_amdgcn_s_barrier();                                               \
    asm volatile("s_waitcnt lgkmcnt(0)" ::: "memory");                          \
    __builtin_amdgcn_sched_barrier(0);                                          \
    __builtin_amdgcn_s_setprio(1);                                              \
    _Pragma("unroll")                                                           \
    for (int kk = 0; kk < 2; ++kk)                                              \
        _Pragma("unroll")                                                       \
        for (int m = 0; m < 4; ++m)                                             \
            _Pragma("unroll")                                                   \
            for (int n = 0; n < 2; ++n)                                         \
                acc[(MH)*4+m][(NH)*2+n] = __builtin_amdgcn_mfma_f32_16x16x32_bf16( \
                    af[kk][m], bfr[kk][n], acc[(MH)*4+m][(NH)*2+n], 0, 0, 0);   \
    __builtin_amdgcn_s_setprio(0);                                              \
    __builtin_amdgcn_sched_barrier(0);                                          \
    if (EB) __builtin_amdgcn_s_barrier();                                       \
} while (0)

template <int MODE>
__global__ __launch_bounds__(512, 2)
void gemm256_kernel(const unsigned short* __restrict__ A,   // M x 4096 bf16
                    const unsigned short* __restrict__ Bt,  // 4096 x 4096 bf16 (N x K)
                    void* __restrict__ Cout)
{
    __shared__ unsigned short L[65536];  // 128 KiB: buf0{A,B} buf1{A,B}
    const char* Lc = (const char*)L;

    const int tid  = threadIdx.x;
    const int lane = tid & 63;
    const int fr   = lane & 15;
    const int fg   = lane >> 4;
    const int wave = tid >> 6;
    const int wr   = wave >> 2;    // 0..1
    const int wc   = wave & 3;     // 0..3

    // XCD swizzle (grid = 512, divisible by 8)
    int wg = blockIdx.x;
    const int per = gridDim.x >> 3;
    wg = (wg & 7) * per + (wg >> 3);
    const int tm = wg >> 4;        // 32 M-tiles
    const int tn = wg & 15;        // 16 N-tiles

    const size_t arow0 = (size_t)tm * 256;
    const size_t brow0 = (size_t)tn * 256;

    // staging: thread tid handles round-row rq = tid>>3, 16B chunk tid&7.
    const int rq = tid >> 3;
    const int wq = (tid >> 6) << 3;
    const int srcoff = (((tid & 7) ^ ((tid >> 3) & 7)) << 3);

    auto stageA = [&](int sb, int c, int kt) {
        #pragma unroll
        for (int q = 0; q < 2; ++q) {
            const int dr = c * 64 + q * 128 + rq;
            gload16(A + ((arow0 + dr) << 12) + kt + srcoff,
                    (void*)&L[sb + ((c * 64 + q * 128 + wq) << 6)]);
        }
    };
    auto stageB = [&](int sb, int c, int kt) {
        #pragma unroll
        for (int q = 0; q < 2; ++q) {
            const int lr  = q * 64 + rq;
            const int dr  = c * 32 + (lr & 31) + (lr >> 5) * 64;
            const int wlr = q * 64 + wq;
            const int wdr = c * 32 + (wlr & 31) + (wlr >> 5) * 64;
            gload16(Bt + ((brow0 + dr) << 12) + kt + srcoff,
                    (void*)&L[sb + 16384 + (wdr << 6)]);
        }
    };

    // precomputed ds_read byte addresses (swizzle + buffer bit folded in)
    const int kx0 = fg << 4;
    const int kx1 = (4 + fg) << 4;
    int ab[8], bb[4];
    #pragma unroll
    for (int m = 0; m < 8; ++m) {
        const int r = wr * 128 + m * 16 + fr;
        ab[m] = r * 128 + ((r & 7) << 4);
    }
    #pragma unroll
    for (int n = 0; n < 4; ++n) {
        const int r = wc * 64 + n * 16 + fr;
        bb[n] = 32768 + r * 128 + ((r & 7) << 4);
    }

    short8 af[2][4], bfr[2][2];
    f32x4 acc[8][4];
    #pragma unroll
    for (int m = 0; m < 8; ++m)
        #pragma unroll
        for (int n = 0; n < 4; ++n)
            acc[m][n] = (f32x4){0.f, 0.f, 0.f, 0.f};

    // prologue: tile 0 into buf0; vmcnt(4) leaves newest {B1,A1} in flight
    stageA(0, 0, 0); stageB(0, 0, 0); stageB(0, 1, 0); stageA(0, 1, 0);
    asm volatile("s_waitcnt vmcnt(4)" ::: "memory");
    __builtin_amdgcn_s_barrier();
    __builtin_amdgcn_sched_barrier(0);

    for (int t = 0; t < 63; ++t) {
        const int sb  = ((t & 1) ^ 1) * 32768;  // u16 index of stage buffer
        const int kt1 = (t + 1) * 64;
        PHASE(0, 0, 1, 1, stageA(sb, 0, kt1), 0);
        PHASE(0, 1, 0, 1, stageB(sb, 0, kt1), 0);
        PHASE(1, 1, 1, 0, stageB(sb, 1, kt1), 0);
        PHASE(1, 0, 0, 1, stageA(sb, 1, kt1), 1);
        #pragma unroll
        for (int i = 0; i < 8; ++i) ab[i] ^= 65536;
        #pragma unroll
        for (int i = 0; i < 4; ++i) bb[i] ^= 65536;
    }
    // tail tile 63 (bases already point at buf1), no staging
    asm volatile("s_waitcnt vmcnt(0)" ::: "memory");
    __builtin_amdgcn_s_barrier();
    __builtin_amdgcn_sched_barrier(0);
    PHASE(0, 0, 1, 1, (void)0, 0);
    PHASE(0, 1, 0, 1, (void)0, 0);
    PHASE(1, 1, 1, 0, (void)0, 0);
    PHASE(1, 0, 0, 1, (void)0, 0);

    // epilogue. C/D layout: col = lane&15, row = (lane>>4)*4 + reg.
    if (MODE == 1) {
        // LDS-staged coalesced bf16 store: 2 passes of 128 rows x 256 cols.
        // LDS stride 260 u16 (520 B) -> fg groups hit bank offsets {0,8,16,24}:
        // conflict-free writes; reads are dense linear rows.
        unsigned short* S = (unsigned short*)L;
        unsigned short* C16 = (unsigned short*)Cout;
        #pragma unroll
        for (int pass = 0; pass < 2; ++pass) {
            __syncthreads();   // LDS free (prev pass copy / K-loop reads done)
            if (wr == pass) {
                #pragma unroll
                for (int m = 0; m < 8; ++m) {
                    #pragma unroll
                    for (int n = 0; n < 4; ++n) {
                        #pragma unroll
                        for (int j = 0; j < 4; ++j) {
                            const int rr = m * 16 + fg * 4 + j;
                            const int cc = wc * 64 + n * 16 + fr;
                            float v = fmaxf(acc[m][n][j], 0.0f) * 2.0f;
                            S[rr * 260 + cc] = f2bf(v);
                        }
                    }
                }
            }
            __syncthreads();
            // copy out: 128 rows x 512 B, fully coalesced 16B/lane
            #pragma unroll
            for (int it = 0; it < 8; ++it) {
                const int idx = it * 4096 + tid * 8;   // u16 flat index
                const int rr  = idx >> 8;
                const int cc  = idx & 255;
                short8 v = *(const short8*)(&S[rr * 260 + cc]);
                const size_t row = (size_t)(tm * 256 + pass * 128 + rr);
                *(short8*)(&C16[(row << 12) + tn * 256 + cc]) = v;
            }
        }
    } else {
        const int orow0 = tm * 256 + wr * 128;
        const int ocol0 = tn * 256 + wc * 64;
        #pragma unroll
        for (int m = 0; m < 8; ++m) {
            #pragma unroll
            for (int n = 0; n < 4; ++n) {
                #pragma unroll
                for (int j = 0; j < 4; ++j) {
                    const int row = orow0 + m * 16 + fg * 4 + j;
                    const int col = ocol0 + n * 16 + fr;
                    ((float*)Cout)[((size_t)row << 12) + col] = acc[m][n][j];
                }
            }
        }
    }
}

// ---------------------------------------------------------------------------
extern "C" void kernel_launch(void* const* d_in, const int* in_sizes, int n_in,
                              void* d_out, int out_size, void* d_ws, size_t ws_size,
                              hipStream_t stream) {
    const float* x  = (const float*)d_in[0];
    const void*  k0 = d_in[1];
    const float* s0 = (const float*)d_in[2];
    const void*  k1 = d_in[3];
    const float* s1 = (const float*)d_in[4];
    const void*  k2 = d_in[5];
    const float* s2 = (const float*)d_in[6];

    const int M = in_sizes[0] / DD;   // 8192

    const size_t act_bytes = (size_t)M * DD * 2;
    const size_t w_bytes   = (size_t)DD * DD * 2;
    const size_t need      = act_bytes * 2 + w_bytes + 256;
    if (ws_size < need) return;

    char* ws = (char*)d_ws;
    unsigned short* xb = (unsigned short*)ws;                        // M x DD bf16 (later h2)
    unsigned short* h1 = (unsigned short*)(ws + act_bytes);          // M x DD bf16
    unsigned short* wt = (unsigned short*)(ws + act_bytes * 2);      // DD x DD bf16 (N x K)
    int* flag          = (int*)(ws + act_bytes * 2 + w_bytes);

    detect_kernel<<<1, 64, 0, stream>>>((const unsigned int*)k0, flag);
    pack_x_kernel<<<2048, 256, 0, stream>>>(x, xb, M * DD / 8);

    dim3 pw_grid(DD / 64, DD / 64);
    const int gemm_grid = (M / 256) * (DD / 256);   // 512

    // layer 0: h1 = relu(s0 * x @ W0) * 2
    pack_w_kernel<<<pw_grid, 256, 0, stream>>>(k0, wt, s0, 1.0f, DD, flag);
    gemm256_kernel<1><<<gemm_grid, 512, 0, stream>>>(xb, wt, h1);

    // layer 1: h2 = relu(ei_dense(h1, k1, s1)) * 2
    pack_w_kernel<<<pw_grid, 256, 0, stream>>>(k1, wt, s1, -4.0f, NE_IDX, flag);
    gemm256_kernel<1><<<gemm_grid, 512, 0, stream>>>(h1, wt, xb);

    // layer 2: out = ei_dense(h2, k2, s2), fp32
    pack_w_kernel<<<pw_grid, 256, 0, stream>>>(k2, wt, s2, -4.0f, NE_IDX, flag);
    gemm256_kernel<0><<<gemm_grid, 512, 0, stream>>>(xb, wt, (float*)d_out);
}

// Round 11
// 715.669 us; speedup vs baseline: 19.5344x; 1.0175x over previous
//
#include <hip/hip_runtime.h>
#include <stdint.h>

// D = 4096, TOKENS = (4,2048) -> M = 8192.
#define DD 4096
#define NE_IDX 3277   // round(4096*0.8)

typedef __attribute__((ext_vector_type(8))) short short8;
typedef __attribute__((ext_vector_type(4))) float f32x4;
typedef __attribute__((ext_vector_type(4))) unsigned int u32x4;

__device__ __forceinline__ unsigned short f2bf(float f) {
    unsigned int u = __float_as_uint(f);
    u += 0x7fffu + ((u >> 16) & 1u);
    return (unsigned short)(u >> 16);
}

__device__ __forceinline__ void gload16(const void* g, void* l) {
    __builtin_amdgcn_global_load_lds(
        (const __attribute__((address_space(1))) unsigned int*)g,
        (__attribute__((address_space(3))) unsigned int*)l,
        16, 0, 0);
}

// ---------------------------------------------------------------------------
__global__ void detect_kernel(const unsigned int* __restrict__ k0, int* __restrict__ flag) {
    if (blockIdx.x == 0 && threadIdx.x == 0) {
        int ok4 = 1;
        for (int i = 0; i < 256; ++i) {
            unsigned int v = k0[i];
            if (!(v == 0u || v == 1u || v == 0x3f800000u)) { ok4 = 0; break; }
        }
        *flag = ok4;
    }
}

// ---------------------------------------------------------------------------
__global__ void pack_x_kernel(const float* __restrict__ x, unsigned short* __restrict__ xb, int n8) {
    const int stride = gridDim.x * blockDim.x;
    for (int i = blockIdx.x * blockDim.x + threadIdx.x; i < n8; i += stride) {
        const float4* p = (const float4*)(x + (size_t)i * 8);
        float4 a = p[0], b = p[1];
        short8 r;
        r[0] = (short)f2bf(a.x); r[1] = (short)f2bf(a.y);
        r[2] = (short)f2bf(a.z); r[3] = (short)f2bf(a.w);
        r[4] = (short)f2bf(b.x); r[5] = (short)f2bf(b.y);
        r[6] = (short)f2bf(b.z); r[7] = (short)f2bf(b.w);
        *(short8*)(xb + (size_t)i * 8) = r;
    }
}

// ---------------------------------------------------------------------------
// wt[j*DD + i] = s * (i < ne ? 1 : inh) * (k[i][j] ? 1 : -1), 64x64 LDS transpose
// ---------------------------------------------------------------------------
__global__ void pack_w_kernel(const void* __restrict__ kin, unsigned short* __restrict__ wt,
                              const float* __restrict__ sptr, float inh, int ne,
                              const int* __restrict__ flag) {
    __shared__ unsigned short tile[64][68];
    const int elem4 = *flag;
    const float s = *sptr;
    const int i0 = blockIdx.x * 64;
    const int j0 = blockIdx.y * 64;
    const int t = threadIdx.x;
    {
        const int il = t >> 2;
        const int jc = (t & 3) * 16;
        const int gi = i0 + il;
        const float mag = s * ((gi < ne) ? 1.0f : inh);
        const unsigned short pos = f2bf(mag);
        const unsigned short neg = f2bf(-mag);
        if (elem4) {
            const unsigned int* k32 = (const unsigned int*)kin + (size_t)gi * DD + j0 + jc;
            #pragma unroll
            for (int q = 0; q < 4; ++q) {
                u32x4 v = *(const u32x4*)(k32 + q * 4);
                #pragma unroll
                for (int e = 0; e < 4; ++e)
                    tile[il][jc + q * 4 + e] = v[e] ? pos : neg;
            }
        } else {
            const unsigned char* k8 = (const unsigned char*)kin + (size_t)gi * DD + j0 + jc;
            u32x4 v = *(const u32x4*)k8;
            #pragma unroll
            for (int q = 0; q < 4; ++q) {
                unsigned int w = v[q];
                tile[il][jc + q * 4 + 0] = (w & 0xffu) ? pos : neg;
                tile[il][jc + q * 4 + 1] = ((w >> 8) & 0xffu) ? pos : neg;
                tile[il][jc + q * 4 + 2] = ((w >> 16) & 0xffu) ? pos : neg;
                tile[il][jc + q * 4 + 3] = ((w >> 24) & 0xffu) ? pos : neg;
            }
        }
    }
    __syncthreads();
    {
        const int jl = t >> 2;
        const int ic = (t & 3) * 16;
        short8 o0, o1;
        #pragma unroll
        for (int e = 0; e < 8; ++e) o0[e] = (short)tile[ic + e][jl];
        #pragma unroll
        for (int e = 0; e < 8; ++e) o1[e] = (short)tile[ic + 8 + e][jl];
        unsigned short* dst = wt + (size_t)(j0 + jl) * DD + i0 + ic;
        *(short8*)(dst) = o0;
        *(short8*)(dst + 8) = o1;
    }
}

// ---------------------------------------------------------------------------
// R3 structure with RELAXED SYNC: 256x256 tile, BK=64, 8 waves (2Mx4N),
// 16x16x32 MFMA, 4 phases/K-tile, but only TWO barriers per tile:
//   mid   (after p1): vmcnt(4)+BAR  -> retires A1(t) before p2 reads af1
//   bound (after p3): vmcnt(2)+BAR  -> retires A0',B0',B1' before next tile
// Reads during t touch buf[t&1] only; stages touch buf[(t+1)&1] only ->
// no intra-tile WAR, so these two visibility deadlines are the only sync
// needed. Waves free-run up to ~2 phases -> one wave's ds_read bunch
// overlaps another's MFMA bunch (desync overlap, cf. m97 multi-block).
// Stage order A0',B0',B1',A1' at p0..p3. FIFO: at bound, 8 outstanding,
// vmcnt(2) leaves A1' (= prologue invariant). At mid, 6 outstanding
// (A1(t),A0',B0'), vmcnt(4) retires A1(t). All deadlines verified.
// ---------------------------------------------------------------------------
#define PHASE(MH, NH, LA, LB, STAGE_STMT, SYNC) do {                            \
    if (LA) {                                                                   \
        _Pragma("unroll")                                                       \
        for (int m = 0; m < 4; ++m) {                                           \
            af[0][m] = *(const short8*)(Lc + (ab[(MH)*4+m] ^ kx0));             \
            af[1][m] = *(const short8*)(Lc + (ab[(MH)*4+m] ^ kx1));             \
        }                                                                       \
    }                                                                           \
    if (LB) {                                                                   \
        _Pragma("unroll")                                                       \
        for (int n = 0; n < 2; ++n) {                                           \
            bfr[0][n] = *(const short8*)(Lc + (bb[(NH)*2+n] ^ kx0));            \
            bfr[1][n] = *(const short8*)(Lc + (bb[(NH)*2+n] ^ kx1));            \
        }                                                                       \
    }                                                                           \
    STAGE_STMT;                                                                 \
    asm volatile("s_waitcnt lgkmcnt(0)" ::: "memory");                          \
    __builtin_amdgcn_sched_barrier(0);                                          \
    __builtin_amdgcn_s_setprio(1);                                              \
    _Pragma("unroll")                                                           \
    for (int kk = 0; kk < 2; ++kk)                                              \
        _Pragma("unroll")                                                       \
        for (int m = 0; m < 4; ++m)                                             \
            _Pragma("unroll")                                                   \
            for (int n = 0; n < 2; ++n)                                         \
                acc[(MH)*4+m][(NH)*2+n] = __builtin_amdgcn_mfma_f32_16x16x32_bf16( \
                    af[kk][m], bfr[kk][n], acc[(MH)*4+m][(NH)*2+n], 0, 0, 0);   \
    __builtin_amdgcn_s_setprio(0);                                              \
    __builtin_amdgcn_sched_barrier(0);                                          \
    if ((SYNC) == 1) asm volatile("s_waitcnt vmcnt(4)" ::: "memory");           \
    if ((SYNC) == 2) asm volatile("s_waitcnt vmcnt(2)" ::: "memory");           \
    if ((SYNC) == 3) asm volatile("s_waitcnt vmcnt(0)" ::: "memory");           \
    if (SYNC) { __builtin_amdgcn_s_barrier();                                   \
                __builtin_amdgcn_sched_barrier(0); }                            \
} while (0)

template <int MODE>
__global__ __launch_bounds__(512, 2)
void gemm256_kernel(const unsigned short* __restrict__ A,   // M x 4096 bf16
                    const unsigned short* __restrict__ Bt,  // 4096 x 4096 bf16 (N x K)
                    void* __restrict__ Cout)
{
    __shared__ unsigned short L[65536];  // 128 KiB: buf0{A,B} buf1{A,B}
    const char* Lc = (const char*)L;

    const int tid  = threadIdx.x;
    const int lane = tid & 63;
    const int fr   = lane & 15;
    const int fg   = lane >> 4;
    const int wave = tid >> 6;
    const int wr   = wave >> 2;    // 0..1
    const int wc   = wave & 3;     // 0..3

    // XCD swizzle (grid = 512, divisible by 8)
    int wg = blockIdx.x;
    const int per = gridDim.x >> 3;
    wg = (wg & 7) * per + (wg >> 3);
    const int tm = wg >> 4;        // 32 M-tiles
    const int tn = wg & 15;        // 16 N-tiles

    const size_t arow0 = (size_t)tm * 256;
    const size_t brow0 = (size_t)tn * 256;

    // staging: thread tid handles round-row rq = tid>>3, 16B chunk tid&7.
    const int rq = tid >> 3;
    const int wq = (tid >> 6) << 3;
    const int srcoff = (((tid & 7) ^ ((tid >> 3) & 7)) << 3);

    auto stageA = [&](int sb, int c, int kt) {
        #pragma unroll
        for (int q = 0; q < 2; ++q) {
            const int dr = c * 64 + q * 128 + rq;
            gload16(A + ((arow0 + dr) << 12) + kt + srcoff,
                    (void*)&L[sb + ((c * 64 + q * 128 + wq) << 6)]);
        }
    };
    auto stageB = [&](int sb, int c, int kt) {
        #pragma unroll
        for (int q = 0; q < 2; ++q) {
            const int lr  = q * 64 + rq;
            const int dr  = c * 32 + (lr & 31) + (lr >> 5) * 64;
            const int wlr = q * 64 + wq;
            const int wdr = c * 32 + (wlr & 31) + (wlr >> 5) * 64;
            gload16(Bt + ((brow0 + dr) << 12) + kt + srcoff,
                    (void*)&L[sb + 16384 + (wdr << 6)]);
        }
    };

    // precomputed ds_read byte addresses (swizzle + buffer bit folded in)
    const int kx0 = fg << 4;
    const int kx1 = (4 + fg) << 4;
    int ab[8], bb[4];
    #pragma unroll
    for (int m = 0; m < 8; ++m) {
        const int r = wr * 128 + m * 16 + fr;
        ab[m] = r * 128 + ((r & 7) << 4);
    }
    #pragma unroll
    for (int n = 0; n < 4; ++n) {
        const int r = wc * 64 + n * 16 + fr;
        bb[n] = 32768 + r * 128 + ((r & 7) << 4);
    }

    short8 af[2][4], bfr[2][2];
    f32x4 acc[8][4];
    #pragma unroll
    for (int m = 0; m < 8; ++m)
        #pragma unroll
        for (int n = 0; n < 4; ++n)
            acc[m][n] = (f32x4){0.f, 0.f, 0.f, 0.f};

    // prologue: tile 0 sites A0,B0,B1,A1 -> buf0; vmcnt(2) retires A0,B0,B1;
    // A1(0) stays in flight == boundary invariant.
    stageA(0, 0, 0); stageB(0, 0, 0); stageB(0, 1, 0); stageA(0, 1, 0);
    asm volatile("s_waitcnt vmcnt(2)" ::: "memory");
    __builtin_amdgcn_s_barrier();
    __builtin_amdgcn_sched_barrier(0);

    for (int t = 0; t < 63; ++t) {
        const int sb  = ((t & 1) ^ 1) * 32768;  // u16 index of stage buffer
        const int kt1 = (t + 1) * 64;
        PHASE(0, 0, 1, 1, stageA(sb, 0, kt1), 0);
        PHASE(0, 1, 0, 1, stageB(sb, 0, kt1), 1);   // mid: vmcnt(4)+BAR
        PHASE(1, 1, 1, 0, stageB(sb, 1, kt1), 0);
        PHASE(1, 0, 0, 1, stageA(sb, 1, kt1), 2);   // bound: vmcnt(2)+BAR
        #pragma unroll
        for (int i = 0; i < 8; ++i) ab[i] ^= 65536;
        #pragma unroll
        for (int i = 0; i < 4; ++i) bb[i] ^= 65536;
    }
    // tail tile 63 (bases point at buf1), no staging; mid drains A1(63)
    PHASE(0, 0, 1, 1, (void)0, 0);
    PHASE(0, 1, 0, 1, (void)0, 3);                  // vmcnt(0)+BAR
    PHASE(1, 1, 1, 0, (void)0, 0);
    PHASE(1, 0, 0, 1, (void)0, 0);

    // epilogue (direct stores): C/D col = lane&15, row = (lane>>4)*4 + reg
    const int orow0 = tm * 256 + wr * 128;
    const int ocol0 = tn * 256 + wc * 64;
    #pragma unroll
    for (int m = 0; m < 8; ++m) {
        #pragma unroll
        for (int n = 0; n < 4; ++n) {
            #pragma unroll
            for (int j = 0; j < 4; ++j) {
                const int row = orow0 + m * 16 + fg * 4 + j;
                const int col = ocol0 + n * 16 + fr;
                float v = acc[m][n][j];
                if (MODE == 1) {
                    v = fmaxf(v, 0.0f) * 2.0f;
                    ((unsigned short*)Cout)[((size_t)row << 12) + col] = f2bf(v);
                } else {
                    ((float*)Cout)[((size_t)row << 12) + col] = v;
                }
            }
        }
    }
}

// ---------------------------------------------------------------------------
extern "C" void kernel_launch(void* const* d_in, const int* in_sizes, int n_in,
                              void* d_out, int out_size, void* d_ws, size_t ws_size,
                              hipStream_t stream) {
    const float* x  = (const float*)d_in[0];
    const void*  k0 = d_in[1];
    const float* s0 = (const float*)d_in[2];
    const void*  k1 = d_in[3];
    const float* s1 = (const float*)d_in[4];
    const void*  k2 = d_in[5];
    const float* s2 = (const float*)d_in[6];

    const int M = in_sizes[0] / DD;   // 8192

    const size_t act_bytes = (size_t)M * DD * 2;
    const size_t w_bytes   = (size_t)DD * DD * 2;
    const size_t need      = act_bytes * 2 + w_bytes + 256;
    if (ws_size < need) return;

    char* ws = (char*)d_ws;
    unsigned short* xb = (unsigned short*)ws;                        // M x DD bf16 (later h2)
    unsigned short* h1 = (unsigned short*)(ws + act_bytes);          // M x DD bf16
    unsigned short* wt = (unsigned short*)(ws + act_bytes * 2);      // DD x DD bf16 (N x K)
    int* flag          = (int*)(ws + act_bytes * 2 + w_bytes);

    detect_kernel<<<1, 64, 0, stream>>>((const unsigned int*)k0, flag);
    pack_x_kernel<<<2048, 256, 0, stream>>>(x, xb, M * DD / 8);

    dim3 pw_grid(DD / 64, DD / 64);
    const int gemm_grid = (M / 256) * (DD / 256);   // 512

    // layer 0: h1 = relu(s0 * x @ W0) * 2
    pack_w_kernel<<<pw_grid, 256, 0, stream>>>(k0, wt, s0, 1.0f, DD, flag);
    gemm256_kernel<1><<<gemm_grid, 512, 0, stream>>>(xb, wt, h1);

    // layer 1: h2 = relu(ei_dense(h1, k1, s1)) * 2
    pack_w_kernel<<<pw_grid, 256, 0, stream>>>(k1, wt, s1, -4.0f, NE_IDX, flag);
    gemm256_kernel<1><<<gemm_grid, 512, 0, stream>>>(h1, wt, xb);

    // layer 2: out = ei_dense(h2, k2, s2), fp32
    pack_w_kernel<<<pw_grid, 256, 0, stream>>>(k2, wt, s2, -4.0f, NE_IDX, flag);
    gemm256_kernel<0><<<gemm_grid, 512, 0, stream>>>(xb, wt, (float*)d_out);
}